// Round 7
// baseline (176.304 us; speedup 1.0000x reference)
//
#include <hip/hip_runtime.h>
#include <hip/hip_bf16.h>

typedef __attribute__((ext_vector_type(8))) short short8;   // 8 bf16 (4 VGPRs)
typedef __attribute__((ext_vector_type(4))) float floatx4;  // MFMA C/D

// (B,T,D) = (128,1024,64) fp32. out[i][j][t] = prod_{s<=t}(1 + <dX(s-1),dY(s-1)>/dt)
constexpr int BX    = 128;
constexpr int TT    = 1024;
constexpr int DDIM  = 64;
constexpr int NPAIR = BX * BX;
constexpr int LCH   = 16;              // t-steps per block
constexpr int NCH   = TT / LCH;        // 64
constexpr float DT_INV = 1023.0f;

// LDS element index for bf16 rows of 64 with XOR-segment swizzle (16B segments).
__device__ __forceinline__ int sidxE(int row, int k) {
    return row * 64 + ((((k >> 3) ^ (row & 7)) << 3) | (k & 7));
}

__device__ __forceinline__ ushort f2bf(float f) {           // round-to-nearest-even bf16
    uint u = __builtin_bit_cast(uint, f);
    u += 0x7fffu + ((u >> 16) & 1u);
    return (ushort)(u >> 16);
}

// 8 floats -> hi/lo bf16 split via packed bf16 converts, two 16B LDS stores.
__device__ __forceinline__ void cvt_store(ushort* hiP, ushort* loP, const float* v) {
    uint hw[4], lw[4];
#pragma unroll
    for (int p = 0; p < 4; ++p) {
        const __hip_bfloat162 h = __float22bfloat162_rn(make_float2(v[2 * p], v[2 * p + 1]));
        const float r0 = v[2 * p]     - __bfloat162float(h.x);
        const float r1 = v[2 * p + 1] - __bfloat162float(h.y);
        const __hip_bfloat162 l = __float22bfloat162_rn(make_float2(r0, r1));
        hw[p] = (uint)__bfloat16_as_ushort(h.x) | ((uint)__bfloat16_as_ushort(h.y) << 16);
        lw[p] = (uint)__bfloat16_as_ushort(l.x) | ((uint)__bfloat16_as_ushort(l.y) << 16);
    }
    *(uint4*)hiP = make_uint4(hw[0], hw[1], hw[2], hw[3]);
    *(uint4*)loP = make_uint4(lw[0], lw[1], lw[2], lw[3]);
}

__device__ __forceinline__ void ld8(const float* p, float* dst) {
    const float4 a = *(const float4*)p;
    const float4 b = *(const float4*)(p + 4);
    dst[0] = a.x; dst[1] = a.y; dst[2] = a.z; dst[3] = a.w;
    dst[4] = b.x; dst[5] = b.y; dst[6] = b.z; dst[7] = b.w;
}

// Kernel A: 32i x 32j pair tile x 16 t-steps. Split-bf16 3-term MFMA dots.
// 1024 blocks = 4/CU (LDS 32KB, VGPR<=128), XCD-grouped: linearID%8 == cz%8.
// Wave w owns the (w>>1, w&1) 16x16 subtile. WP=1: history -> W[cz][pair][16]
// (1KB contiguous full-line stores); WP=0: legacy direct [pair][t] 64B stores.
template<int WP>
__global__ __launch_bounds__(256, 4) void zchunk_kernel(const float* __restrict__ X,
                                                        const float* __restrict__ Y,
                                                        float* __restrict__ dst,
                                                        float* __restrict__ P)
{
    __shared__ __align__(16) ushort smXhi[2][32 * 64], smXlo[2][32 * 64];  // 16 KB
    __shared__ __align__(16) ushort smYhi[2][32 * 64], smYlo[2][32 * 64];  // 16 KB

    // swizzled decode: L = (cz&7) + 8*(tile + 16*(cz>>3))
    const int L    = (int)blockIdx.x;            // 0..1023
    const int tile = (L >> 3) & 15;              // 0..15
    const int cz   = ((L >> 7) << 3) | (L & 7);  // 0..63
    const int i0 = (tile & 3) * 32;
    const int j0 = (tile >> 2) * 32;
    const int t0 = cz * LCH;
    const int tid  = (int)threadIdx.x;
    const int lane = tid & 63, w = tid >> 6, quad = lane >> 4, l15 = lane & 15;
    const int wr = w >> 1, wc = w & 1;

    const int srow = tid >> 3;          // 0..31
    const int sseg = tid & 7;
    const float* xp = X + (size_t)(i0 + srow) * TT * DDIM + sseg * 8;
    const float* yp = Y + (size_t)(j0 + srow) * TT * DDIM + sseg * 8;

    float cx[8], cy[8];                 // slice t0+h values
    float rx[2][8], ry[2][8];           // 2-deep prefetch ring
    {
        const int sa = (t0 == 0) ? 0 : (t0 - 1);
        float pvx[8], pvy[8], d[8];
        ld8(xp + (size_t)t0 * DDIM, cx);
        ld8(yp + (size_t)t0 * DDIM, cy);
        ld8(xp + (size_t)sa * DDIM, pvx);
        ld8(yp + (size_t)sa * DDIM, pvy);
        ld8(xp + (size_t)(t0 + 1) * DDIM, rx[1]);   // slice t0+1 -> set 1
        ld8(yp + (size_t)(t0 + 1) * DDIM, ry[1]);

#pragma unroll
        for (int k = 0; k < 8; ++k) d[k] = cx[k] - pvx[k];
        cvt_store(&smXhi[0][sidxE(srow, sseg * 8)], &smXlo[0][sidxE(srow, sseg * 8)], d);
#pragma unroll
        for (int k = 0; k < 8; ++k) d[k] = cy[k] - pvy[k];
        cvt_store(&smYhi[0][sidxE(srow, sseg * 8)], &smYlo[0][sidxE(srow, sseg * 8)], d);
    }

    float cum[4];
    uint  histP[4][8];                  // bf16-packed 16-step history (static-indexed)
#pragma unroll
    for (int r = 0; r < 4; ++r) cum[r] = 1.f;

    __syncthreads();

#pragma unroll
    for (int h = 0; h < LCH; ++h) {
        const int cur = h & 1;

        if (h + 2 < LCH) {              // prefetch slice t0+h+2 into ring set h&1
            const size_t u = (size_t)(t0 + h + 2) * DDIM;
            ld8(xp + u, rx[h & 1]); ld8(yp + u, ry[h & 1]);
        }

        short8 aHi[2], aLo[2];
#pragma unroll
        for (int kk = 0; kk < 2; ++kk) {
            const int e = sidxE(wr * 16 + l15, kk * 32 + quad * 8);
            aHi[kk] = *(const short8*)&smXhi[cur][e];
            aLo[kk] = *(const short8*)&smXlo[cur][e];
        }

        floatx4 acc = {0.f, 0.f, 0.f, 0.f};
#pragma unroll
        for (int kk = 0; kk < 2; ++kk) {
            const int e = sidxE(wc * 16 + l15, kk * 32 + quad * 8);
            const short8 bHi = *(const short8*)&smYhi[cur][e];
            const short8 bLo = *(const short8*)&smYlo[cur][e];
            acc = __builtin_amdgcn_mfma_f32_16x16x32_bf16(aLo[kk], bHi, acc, 0, 0, 0);
            acc = __builtin_amdgcn_mfma_f32_16x16x32_bf16(aHi[kk], bLo, acc, 0, 0, 0);
            acc = __builtin_amdgcn_mfma_f32_16x16x32_bf16(aHi[kk], bHi, acc, 0, 0, 0);
        }
#pragma unroll
        for (int r = 0; r < 4; ++r) {
            cum[r] *= fmaf(acc[r], DT_INV, 1.f);
            const uint hb = (uint)f2bf(cum[r]);
            if ((h & 1) == 0) histP[r][h >> 1] = hb;
            else              histP[r][h >> 1] |= (hb << 16);
        }

        if (h + 1 < LCH) {              // stage next step's diffs into other buffer
            const int nsel = (h + 1) & 1;
            float d[8];
#pragma unroll
            for (int k = 0; k < 8; ++k) d[k] = rx[nsel][k] - cx[k];
            cvt_store(&smXhi[cur ^ 1][sidxE(srow, sseg * 8)], &smXlo[cur ^ 1][sidxE(srow, sseg * 8)], d);
#pragma unroll
            for (int k = 0; k < 8; ++k) d[k] = ry[nsel][k] - cy[k];
            cvt_store(&smYhi[cur ^ 1][sidxE(srow, sseg * 8)], &smYlo[cur ^ 1][sidxE(srow, sseg * 8)], d);
#pragma unroll
            for (int k = 0; k < 8; ++k) { cx[k] = rx[nsel][k]; cy[k] = ry[nsel][k]; }
            __syncthreads();
        }
    }

    // Epilogue: fp32 chunk totals + UNSCALED bf16 history.
#pragma unroll
    for (int r = 0; r < 4; ++r) {
        const int pair = (i0 + wr * 16 + quad * 4 + r) * BX + (j0 + wc * 16 + l15);
        P[(size_t)cz * NPAIR + pair] = cum[r];
        float* o = WP ? (dst + ((size_t)cz * NPAIR + pair) * LCH)   // W[cz][pair][16]
                      : (dst + (size_t)pair * TT + t0);             // out[pair][t]
#pragma unroll
        for (int q = 0; q < 4; ++q) {
            const uint u0 = histP[r][2 * q];
            const uint u1 = histP[r][2 * q + 1];
            *(float4*)(o + q * 4) = make_float4(
                __builtin_bit_cast(float, u0 << 16),
                __builtin_bit_cast(float, u0 & 0xffff0000u),
                __builtin_bit_cast(float, u1 << 16),
                __builtin_bit_cast(float, u1 & 0xffff0000u));
        }
    }
}

// Kernel B (W-path) v3: block = 16 pairs, 1024 blocks = 4/CU.
// Phase 1: parallel exclusive chunk-prefix (16 segs x 16 pairs, 4-chunk local
//          prefix + LDS combine) -> pf[64][pair].
// Phase 2: wave wv walks chunks wv*16..+15; lanes (pr,tq) read W[c][p0..p0+15][..]
//          as ONE contiguous 1KB wave-load; stores walk adjacent 64B of each
//          out row (unroll 2 completes 128B lines back-to-back).
__global__ __launch_bounds__(256) void scanscale_w(float* __restrict__ out,
                                                   const float* __restrict__ W,
                                                   const float* __restrict__ P)
{
    __shared__ float pf[NCH][17];       // [chunk][pair] padded
    __shared__ float tot[16][17];       // [seg][pair]

    const int p0  = (int)blockIdx.x * 16;
    const int tid = (int)threadIdx.x;
    const int p   = tid & 15;           // pair 0..15
    const int seg = tid >> 4;           // 0..15 (chunks seg*4..+3)

    float v[4], e[4];
#pragma unroll
    for (int k = 0; k < 4; ++k)
        v[k] = P[(size_t)(seg * 4 + k) * NPAIR + p0 + p];
    e[0] = 1.f;
#pragma unroll
    for (int k = 1; k < 4; ++k) e[k] = e[k - 1] * v[k - 1];
    tot[seg][p] = e[3] * v[3];
    __syncthreads();

    float base = 1.f;
#pragma unroll
    for (int q = 0; q < 15; ++q)
        if (q < seg) base *= tot[q][p];
#pragma unroll
    for (int k = 0; k < 4; ++k)
        pf[seg * 4 + k][p] = base * e[k];
    __syncthreads();

    const int wv = tid >> 6;            // wave 0..3 -> chunks wv*16..+15
    const int l  = tid & 63;
    const int pr = l >> 2;              // pair 0..15
    const int tq = l & 3;               // float4 slot within chunk-run
    float* orow = out + (size_t)(p0 + pr) * TT + tq * 4;
#pragma unroll 2
    for (int k = 0; k < 16; ++k) {
        const int c = wv * 16 + k;
        const float4 w4 = *(const float4*)(W + ((size_t)c * NPAIR + p0 + pr) * LCH + tq * 4);
        const float f = pf[c][pr];
        *(float4*)(orow + (size_t)c * LCH) =
            make_float4(w4.x * f, w4.y * f, w4.z * f, w4.w * f);
    }
}

// Legacy fallback kernel B: scan+RMW-scale of out in place.
__global__ __launch_bounds__(256) void scanscale_kernel(float* __restrict__ out,
                                                        const float* __restrict__ P)
{
    __shared__ float pf[16][NCH];       // 4 KB
    const int p0  = (int)blockIdx.x * 16;
    const int tid = (int)threadIdx.x;

    if (tid < 16) {
        const int p = p0 + tid;
        float run = 1.f;
#pragma unroll 4
        for (int c = 0; c < NCH; ++c) {
            pf[tid][c] = run;
            run *= P[(size_t)c * NPAIR + p];
        }
    }
    __syncthreads();

    const int pp  = tid >> 4;
    const int col = tid & 15;
    float* row = out + (size_t)(p0 + pp) * TT;
#pragma unroll
    for (int seg = 0; seg < 16; ++seg) {
        const int t = seg * 64 + col * 4;
        const float f = pf[pp][t >> 4];
        float4 v = *(float4*)(row + t);
        v.x *= f; v.y *= f; v.z *= f; v.w *= f;
        *(float4*)(row + t) = v;
    }
}

extern "C" void kernel_launch(void* const* d_in, const int* in_sizes, int n_in,
                              void* d_out, int out_size, void* d_ws, size_t ws_size,
                              hipStream_t stream)
{
    const float* X = (const float*)d_in[0];
    const float* Y = (const float*)d_in[1];
    float* out = (float*)d_out;
    float* P   = (float*)d_ws;                          // 4 MB
    float* W   = (float*)d_ws + (size_t)NCH * NPAIR;    // 64 MB (W[cz][pair][16])

    const size_t need = ((size_t)NCH * NPAIR + (size_t)NPAIR * TT) * sizeof(float);
    if (ws_size >= need) {
        zchunk_kernel<1><<<dim3(1024), 256, 0, stream>>>(X, Y, W, P);
        scanscale_w<<<dim3(NPAIR / 16), 256, 0, stream>>>(out, W, P);
    } else {
        zchunk_kernel<0><<<dim3(1024), 256, 0, stream>>>(X, Y, out, P);
        scanscale_kernel<<<dim3(NPAIR / 16), 256, 0, stream>>>(out, P);
    }
}